// Round 1
// baseline (463.136 us; speedup 1.0000x reference)
//
#include <hip/hip_runtime.h>
#include <stdint.h>

typedef __attribute__((ext_vector_type(8))) __bf16 bf16x8;
typedef __attribute__((ext_vector_type(4))) float f32x4;
typedef __attribute__((ext_vector_type(8))) unsigned short us8;

// ---------- helpers ----------
__device__ __forceinline__ unsigned short f2bf(float f) {
  unsigned u = __float_as_uint(f);
  unsigned r = u + 0x7fffu + ((u >> 16) & 1u);   // RNE
  return (unsigned short)(r >> 16);
}

__device__ __forceinline__ void gload16(const void* gptr, void* lptr) {
  __builtin_amdgcn_global_load_lds(
      (const __attribute__((address_space(1))) void*)gptr,
      (__attribute__((address_space(3))) void*)lptr, 16, 0, 0);
}

// ---------- prep: wsum[co] = sum over (tap,ci) of conv0^2 ----------
__global__ void k_wsum(const float* __restrict__ conv0, float* __restrict__ wsum) {
  int co = blockIdx.x * 256 + threadIdx.x;      // grid 2 -> 512
  float s = 0.f;
  for (int k = 0; k < 4608; ++k) {
    float v = conv0[(size_t)k * 512 + co];
    s += v * v;
  }
  wsum[co] = s;
}

// ---------- prep: scale[b][co] = s0 * rsqrt(s0^2*wsum + 1e-8) ----------
__global__ void k_scale(const float* __restrict__ w, const float* __restrict__ y0k,
                        const float* __restrict__ y0b, const float* __restrict__ wsum,
                        float* __restrict__ scale) {
  int g = blockIdx.x * 256 + threadIdx.x;       // grid 16 -> 4096 = 8*512
  int b = g >> 9, co = g & 511;
  float s = y0b[co];
  const float* wr = w + b * 512;
  for (int ci = 0; ci < 512; ++ci) s += wr[ci] * y0k[ci * 512 + co];
  scale[g] = s * rsqrtf(s * s * wsum[co] + 1e-8f);
}

// ---------- prep: transpose conv0[tap][ci][co] -> w_t[tap][co][ci] (bf16) ----------
__global__ void k_wt(const float* __restrict__ conv0, unsigned short* __restrict__ wt) {
  __shared__ float tile[64][65];
  int bx = blockIdx.x;                          // 9*64 = 576
  int tap = bx >> 6, rem = bx & 63;
  int ci0 = (rem >> 3) << 6, co0 = (rem & 7) << 6;
  int tx = threadIdx.x & 63, ty4 = threadIdx.x >> 6;   // ty4: 0..3
#pragma unroll
  for (int k = 0; k < 16; ++k) {
    int ci = k * 4 + ty4;
    tile[ci][tx] = conv0[((size_t)(tap * 512 + ci0 + ci)) * 512 + co0 + tx];
  }
  __syncthreads();
#pragma unroll
  for (int k = 0; k < 16; ++k) {
    int co = k * 4 + ty4;
    wt[((size_t)(tap * 512 + co0 + co)) * 512 + ci0 + tx] = f2bf(tile[tx][co]);
  }
}

// ---------- prep: bilinear 2x upsample + zero-pad, f32 -> bf16 ----------
// xpad[b][yy][xx][ci], yy,xx in [0,66): border = 0, interior = upsampled(yy-1, xx-1)
__global__ void k_up(const float* __restrict__ x, unsigned short* __restrict__ xpad) {
  int gid = blockIdx.x * 256 + threadIdx.x;     // total 8*66*66*64 = 2230272
  if (gid >= 8 * 66 * 66 * 64) return;
  int c0 = (gid & 63) << 3;                     // 8 channels per thread
  int pos = gid >> 6;
  int xx = pos % 66;
  int t = pos / 66;
  int yy = t % 66;
  int b = t / 66;
  unsigned short* dst = xpad + (size_t)pos * 512 + c0;
  us8 o;
  if (yy == 0 || yy == 65 || xx == 0 || xx == 65) {
#pragma unroll
    for (int i = 0; i < 8; ++i) o[i] = 0;
  } else {
    int y = yy - 1, xq = xx - 1;
    int jy = y >> 1, jx = xq >> 1;
    int r0, r1, cx0, cx1;
    float ay0, ay1, ax0, ax1;
    if ((y & 1) == 0) {  // even: 0.25*in[j-1] + 0.75*in[j], edge -> in[0]
      r0 = jy > 0 ? jy - 1 : 0; r1 = jy;
      ay0 = jy > 0 ? 0.25f : 0.f; ay1 = jy > 0 ? 0.75f : 1.f;
    } else {             // odd: 0.75*in[j] + 0.25*in[j+1], edge -> in[31]
      r0 = jy; r1 = jy < 31 ? jy + 1 : 31;
      ay0 = jy < 31 ? 0.75f : 1.f; ay1 = jy < 31 ? 0.25f : 0.f;
    }
    if ((xq & 1) == 0) {
      cx0 = jx > 0 ? jx - 1 : 0; cx1 = jx;
      ax0 = jx > 0 ? 0.25f : 0.f; ax1 = jx > 0 ? 0.75f : 1.f;
    } else {
      cx0 = jx; cx1 = jx < 31 ? jx + 1 : 31;
      ax0 = jx < 31 ? 0.75f : 1.f; ax1 = jx < 31 ? 0.25f : 0.f;
    }
    const float* base = x + (size_t)b * 32 * 32 * 512 + c0;
    const float* p00 = base + (size_t)(r0 * 32 + cx0) * 512;
    const float* p01 = base + (size_t)(r0 * 32 + cx1) * 512;
    const float* p10 = base + (size_t)(r1 * 32 + cx0) * 512;
    const float* p11 = base + (size_t)(r1 * 32 + cx1) * 512;
#pragma unroll
    for (int i = 0; i < 8; ++i) {
      float v = ay0 * (ax0 * p00[i] + ax1 * p01[i]) + ay1 * (ax0 * p10[i] + ax1 * p11[i]);
      o[i] = f2bf(v);
    }
  }
  *(us8*)dst = o;
}

// ---------- main: implicit-GEMM 3x3 conv + per-(b,co) scale + epilogue ----------
// Block: 128 pixels (2 image rows) x 128 co. 4 waves: (wr: row, wc: co-half).
// K-loop: 8 ci-chunks of 64; per chunk stage A-halo (4 rows x 66 x 64ch) once,
// then 9 taps each staging B (128co x 64ci) and doing 32 MFMAs/wave.
__global__ __launch_bounds__(256) void k_conv(
    const unsigned short* __restrict__ xpad,
    const unsigned short* __restrict__ wt,
    const float* __restrict__ scale,
    const float* __restrict__ noise,
    const float* __restrict__ ns0, const float* __restrict__ ns1,
    const float* __restrict__ bias0, const float* __restrict__ bias1,
    float* __restrict__ out)
{
  __shared__ __align__(16) unsigned short ldsA[33 * 512];  // 4*66*64 = 16896 elems, 33 KiB
  __shared__ __align__(16) unsigned short ldsB[16 * 512];  // 128*64 = 8192 elems, 16 KiB

  const int tid = threadIdx.x;
  const int wid = tid >> 6;
  const int lane = tid & 63;

  const int bx = blockIdx.x;           // 1024 = 256 mblk * 4 nblk
  const int mblk = bx >> 2;
  const int nblk = bx & 3;
  const int b = mblk >> 5;
  const int y0 = (mblk & 31) << 1;     // first image row of the pair
  const int co_base = nblk << 7;

  const int wr = wid >> 1;             // which image row (0/1)
  const int wc = wid & 1;              // which co half (0/1)

  f32x4 acc[4][4];
#pragma unroll
  for (int i = 0; i < 4; ++i)
#pragma unroll
    for (int j = 0; j < 4; ++j) acc[i][j] = f32x4{0.f, 0.f, 0.f, 0.f};

  const size_t xb = (size_t)b * (66 * 66 * 512);

  for (int kc = 0; kc < 512; kc += 64) {
    __syncthreads();  // prior tap's compute done before restaging A/B
    // ---- stage A halo: padded rows y0..y0+3, xx 0..65, 64 ch. 33 KiB, swizzled src ----
    for (int i = wid; i < 33; i += 4) {
      int g = (i << 6) + lane;         // 16B granule id
      int rx = g >> 3;                 // r*66 + xx
      int r = rx / 66;
      int xx = rx - r * 66;
      int cg = (g & 7) ^ (xx & 7);     // inverse-swizzled source granule
      const unsigned short* src =
          xpad + xb + ((size_t)((y0 + r) * 66 + xx) << 9) + kc + (cg << 3);
      gload16(src, (char*)ldsA + (i << 10));
    }
#pragma unroll
    for (int tap = 0; tap < 9; ++tap) {
      if (tap) __syncthreads();        // prior compute done reading ldsB
      // ---- stage B: w_t[tap][co_base..+128][kc..+64], swizzled src ----
      for (int i = wid; i < 16; i += 4) {
        int g = (i << 6) + lane;
        int co = g >> 3;
        int cg = (g & 7) ^ (co & 7);
        const unsigned short* src =
            wt + (((size_t)(tap * 512 + co_base + co)) << 9) + kc + (cg << 3);
        gload16(src, (char*)ldsB + (i << 10));
      }
      __syncthreads();                 // compiler drains vmcnt before barrier
      const int ky = tap / 3, kx = tap - ky * 3;
      const int r = wr + ky;           // LDS A row 0..3
      const int axor = (((lane & 15) + kx) & 7) << 4;
      const int bxor = (lane & 7) << 4;
#pragma unroll
      for (int kk = 0; kk < 2; ++kk) {
        const int kbyte = ((kk << 5) + ((lane >> 4) << 3)) << 1;  // bytes along K
        bf16x8 af[4], bfr[4];
#pragma unroll
        for (int mi = 0; mi < 4; ++mi) {
          int xx = (mi << 4) + (lane & 15) + kx;
          int off = ((r * 66 + xx) << 7) + (kbyte ^ axor);
          af[mi] = *(const bf16x8*)((const char*)ldsA + off);
        }
#pragma unroll
        for (int ni = 0; ni < 4; ++ni) {
          int co = (wc << 6) + (ni << 4) + (lane & 15);
          int off = (co << 7) + (kbyte ^ bxor);
          bfr[ni] = *(const bf16x8*)((const char*)ldsB + off);
        }
#pragma unroll
        for (int mi = 0; mi < 4; ++mi)
#pragma unroll
          for (int ni = 0; ni < 4; ++ni)
            acc[mi][ni] = __builtin_amdgcn_mfma_f32_16x16x32_bf16(
                af[mi], bfr[ni], acc[mi][ni], 0, 0, 0);
      }
    }
  }

  // ---- epilogue: scale, noise/bias adds, two leaky-relus, fp32 out ----
  const int py = y0 + wr;
  const int colr = lane & 15;          // n within 16 (C/D: col = lane&15)
  const int rowm = (lane >> 4) << 2;   // m base    (C/D: row = (lane>>4)*4 + reg)
  float sc[4], nz[4];
#pragma unroll
  for (int ni = 0; ni < 4; ++ni) {
    int co = co_base + (wc << 6) + (ni << 4) + colr;
    sc[ni] = scale[(b << 9) + co];
    nz[ni] = noise[co];
  }
  const size_t rowbase = ((size_t)((b << 6) + py)) << 6;
#pragma unroll
  for (int mi = 0; mi < 4; ++mi) {
#pragma unroll
    for (int j = 0; j < 4; ++j) {
      int px = (mi << 4) + rowm + j;
      size_t base = ((rowbase + px) << 9) + co_base + (wc << 6) + colr;
#pragma unroll
      for (int ni = 0; ni < 4; ++ni) {
        size_t idx = base + ((size_t)ni << 4);
        float v = acc[mi][ni][j] * sc[ni];
        v += ns0[idx] * nz[ni] + bias0[idx];
        v = fmaxf(v, 0.2f * v);        // leaky_relu(0.2)
        v += ns1[idx] * nz[ni] + bias1[idx];
        v = fmaxf(v, 0.2f * v);
        out[idx] = v;
      }
    }
  }
}

// ---------- launch ----------
extern "C" void kernel_launch(void* const* d_in, const int* in_sizes, int n_in,
                              void* d_out, int out_size, void* d_ws, size_t ws_size,
                              hipStream_t stream) {
  const float* x     = (const float*)d_in[0];
  const float* w     = (const float*)d_in[1];
  const float* noise = (const float*)d_in[2];
  const float* y0k   = (const float*)d_in[3];
  const float* y0b   = (const float*)d_in[4];
  // d_in[5], d_in[6]: y1_kernel/y1_bias — second conv's result is discarded in the
  // reference (missing concat bug) -> skip entirely.
  const float* conv0 = (const float*)d_in[7];
  // d_in[8]: conv1 unused
  const float* ns0   = (const float*)d_in[9];
  const float* ns1   = (const float*)d_in[10];
  const float* bias0 = (const float*)d_in[11];
  const float* bias1 = (const float*)d_in[12];
  float* out = (float*)d_out;

  // workspace layout (bytes):
  //   xpad  bf16 [8][66][66][512] : 35,684,352
  //   w_t   bf16 [9][512][512]    :  4,718,592
  //   scale f32  [8][512]         :     16,384
  //   wsum  f32  [512]            :      2,048
  char* ws = (char*)d_ws;
  unsigned short* xpad = (unsigned short*)ws;
  unsigned short* wtp  = (unsigned short*)(ws + 35684352);
  float* scale = (float*)(ws + 35684352 + 4718592);
  float* wsum  = (float*)(ws + 35684352 + 4718592 + 16384);

  k_wsum<<<2, 256, 0, stream>>>(conv0, wsum);
  k_scale<<<16, 256, 0, stream>>>(w, y0k, y0b, wsum, scale);
  k_wt<<<576, 256, 0, stream>>>(conv0, wtp);
  k_up<<<8712, 256, 0, stream>>>(x, xpad);
  k_conv<<<1024, 256, 0, stream>>>(xpad, wtp, scale, noise, ns0, ns1, bias0, bias1, out);
}

// Round 2
// 233.823 us; speedup vs baseline: 1.9807x; 1.9807x over previous
//
#include <hip/hip_runtime.h>
#include <stdint.h>

typedef __attribute__((ext_vector_type(8))) __bf16 bf16x8;
typedef __attribute__((ext_vector_type(4))) float f32x4;
typedef __attribute__((ext_vector_type(8))) unsigned short us8;

// ---------- helpers ----------
__device__ __forceinline__ unsigned short f2bf(float f) {
  unsigned u = __float_as_uint(f);
  unsigned r = u + 0x7fffu + ((u >> 16) & 1u);   // RNE
  return (unsigned short)(r >> 16);
}

__device__ __forceinline__ void gload16(const void* gptr, void* lptr) {
  __builtin_amdgcn_global_load_lds(
      (const __attribute__((address_space(1))) void*)gptr,
      (__attribute__((address_space(3))) void*)lptr, 16, 0, 0);
}

// ---------- prep: zero wsum ----------
__global__ void k_zero(float* __restrict__ wsum) {
  int i = blockIdx.x * 256 + threadIdx.x;
  if (i < 512) wsum[i] = 0.f;
}

// ---------- prep: pack conv0 -> MFMA B fragments (bf16) + wsum partials ----------
// bpack layout: [chunk(8)][tap(9)][co16(32)][kk(2)][lane(64)][8] bf16
// content: lane l, elem e: co = co16*16 + (l&15); ci = chunk*64 + kk*32 + (l>>4)*8 + e
__global__ void k_bpack(const float* __restrict__ conv0,
                        unsigned short* __restrict__ bpack,
                        float* __restrict__ wsum) {
  __shared__ float tile[64][65];
  int bx = blockIdx.x;                 // 576 = 9 taps * (8 chunk * 8 co-block)
  int tap = bx >> 6, rem = bx & 63;
  int chunk = rem >> 3, cb = rem & 7;
  int ci0 = chunk << 6, co0 = cb << 6;
  int ty = threadIdx.x >> 6, tx = threadIdx.x & 63;
#pragma unroll
  for (int k = 0; k < 16; ++k) {
    int ci = (k << 2) + ty;
    tile[ci][tx] = conv0[((size_t)(tap * 512 + ci0 + ci)) * 512 + co0 + tx];
  }
  __syncthreads();
  // wsum partial: sum of squares over this block's 64 ci, per co
  float p = 0.f;
#pragma unroll
  for (int q = 0; q < 16; ++q) {
    float v = tile[(ty << 4) + q][tx];
    p += v * v;
  }
  atomicAdd(&wsum[co0 + tx], p);
  // pack: 512 fragment-lane slots, 2 per thread
#pragma unroll
  for (int s2 = 0; s2 < 2; ++s2) {
    int slot = (threadIdx.x << 1) + s2;
    int f = slot >> 6, l = slot & 63;
    int co16l = f >> 1, kk = f & 1;
    int col = (co16l << 4) + (l & 15);
    int cil = (kk << 5) + ((l >> 4) << 3);
    us8 o;
#pragma unroll
    for (int e = 0; e < 8; ++e) o[e] = f2bf(tile[cil + e][col]);
    size_t fi = (((size_t)chunk * 9 + tap) * 32 + (cb << 2) + co16l) * 2 + kk;
    *(us8*)(bpack + fi * 512 + (size_t)l * 8) = o;
  }
}

// ---------- prep: scale[b][co] = s0 * rsqrt(s0^2*wsum + 1e-8) ----------
__global__ void k_scale(const float* __restrict__ w, const float* __restrict__ y0k,
                        const float* __restrict__ y0b, const float* __restrict__ wsum,
                        float* __restrict__ scale) {
  int g = blockIdx.x * 256 + threadIdx.x;       // grid 16 -> 4096 = 8*512
  int b = g >> 9, co = g & 511;
  float s = y0b[co];
  const float* wr = w + b * 512;
  for (int ci = 0; ci < 512; ++ci) s += wr[ci] * y0k[ci * 512 + co];
  scale[g] = s * rsqrtf(s * s * wsum[co] + 1e-8f);
}

// ---------- prep: bilinear 2x upsample + zero-pad, f32 -> bf16 ----------
__global__ void k_up(const float* __restrict__ x, unsigned short* __restrict__ xpad) {
  int gid = blockIdx.x * 256 + threadIdx.x;     // total 8*66*66*64 = 2230272
  if (gid >= 8 * 66 * 66 * 64) return;
  int c0 = (gid & 63) << 3;                     // 8 channels per thread
  int pos = gid >> 6;
  int xx = pos % 66;
  int t = pos / 66;
  int yy = t % 66;
  int b = t / 66;
  unsigned short* dst = xpad + (size_t)pos * 512 + c0;
  us8 o;
  if (yy == 0 || yy == 65 || xx == 0 || xx == 65) {
#pragma unroll
    for (int i = 0; i < 8; ++i) o[i] = 0;
  } else {
    int y = yy - 1, xq = xx - 1;
    int jy = y >> 1, jx = xq >> 1;
    int r0, r1, cx0, cx1;
    float ay0, ay1, ax0, ax1;
    if ((y & 1) == 0) { r0 = jy > 0 ? jy - 1 : 0; r1 = jy;
      ay0 = jy > 0 ? 0.25f : 0.f; ay1 = jy > 0 ? 0.75f : 1.f;
    } else { r0 = jy; r1 = jy < 31 ? jy + 1 : 31;
      ay0 = jy < 31 ? 0.75f : 1.f; ay1 = jy < 31 ? 0.25f : 0.f; }
    if ((xq & 1) == 0) { cx0 = jx > 0 ? jx - 1 : 0; cx1 = jx;
      ax0 = jx > 0 ? 0.25f : 0.f; ax1 = jx > 0 ? 0.75f : 1.f;
    } else { cx0 = jx; cx1 = jx < 31 ? jx + 1 : 31;
      ax0 = jx < 31 ? 0.75f : 1.f; ax1 = jx < 31 ? 0.25f : 0.f; }
    const float* base = x + (size_t)b * 32 * 32 * 512 + c0;
    const f32x4* q00 = (const f32x4*)(base + (size_t)(r0 * 32 + cx0) * 512);
    const f32x4* q01 = (const f32x4*)(base + (size_t)(r0 * 32 + cx1) * 512);
    const f32x4* q10 = (const f32x4*)(base + (size_t)(r1 * 32 + cx0) * 512);
    const f32x4* q11 = (const f32x4*)(base + (size_t)(r1 * 32 + cx1) * 512);
#pragma unroll
    for (int h = 0; h < 2; ++h) {
      f32x4 a = q00[h], bb = q01[h], c = q10[h], d = q11[h];
#pragma unroll
      for (int e = 0; e < 4; ++e) {
        float v = ay0 * (ax0 * a[e] + ax1 * bb[e]) + ay1 * (ax0 * c[e] + ax1 * d[e]);
        o[h * 4 + e] = f2bf(v);
      }
    }
  }
  *(us8*)dst = o;
}

// ---------- main: implicit-GEMM 3x3 conv, B-fragments from global regs ----------
// Block: 128 px (2 rows) x 128 co; 4 waves, each 128px x 32co (mi=8, ni=2).
// Per ci-chunk (64): stage A halo once (2 barriers), then 9 taps with B fragments
// double-buffered global->reg (no barriers within taps).
__global__ __launch_bounds__(256) void k_conv(
    const unsigned short* __restrict__ xpad,
    const unsigned short* __restrict__ bpack,
    const float* __restrict__ scale,
    const float* __restrict__ noise,
    const float* __restrict__ ns0, const float* __restrict__ ns1,
    const float* __restrict__ bias0, const float* __restrict__ bias1,
    float* __restrict__ out)
{
  __shared__ __align__(16) unsigned short ldsA[33 * 512];  // 4 rows x 66 x 64ch, 33 KiB

  const int tid = threadIdx.x;
  const int wid = tid >> 6;
  const int lane = tid & 63;
  const int l15 = lane & 15, lhi = lane >> 4;

  // XCD-aware swizzle: consecutive bx round-robin XCDs; give each XCD pair one nblk
  const int bx = blockIdx.x;           // 1024
  const int nblk = (bx >> 1) & 3;
  const int mblk = ((bx >> 3) << 1) | (bx & 1);
  const int b = mblk >> 5;
  const int y0 = (mblk & 31) << 1;
  const int co_base = (nblk << 7) + (wid << 5);   // wave's 32-co slice

  f32x4 acc[8][2];
#pragma unroll
  for (int i = 0; i < 8; ++i) {
    acc[i][0] = f32x4{0.f, 0.f, 0.f, 0.f};
    acc[i][1] = f32x4{0.f, 0.f, 0.f, 0.f};
  }

  const size_t xb = (size_t)b * (66 * 66 * 512);
  bf16x8 bq0[4], bq1[4];               // [ni*2+kk], double-buffered across taps

  for (int chunk = 0; chunk < 8; ++chunk) {
    const int kc = chunk << 6;
    __syncthreads();                   // all waves done reading prior chunk's ldsA
    // ---- stage A halo: rows y0..y0+3 (padded), xx 0..65, 64 ch; swizzled source ----
    for (int i = wid; i < 33; i += 4) {
      int g = (i << 6) + lane;         // 16B granule id
      int rx = g >> 3;
      int r = rx / 66;
      int xx = rx - r * 66;
      int cg = (g & 7) ^ (xx & 7);
      const unsigned short* src =
          xpad + xb + ((size_t)((y0 + r) * 66 + xx) << 9) + kc + (cg << 3);
      gload16(src, (char*)ldsA + (i << 10));
    }
    // wave's B-fragment base for this chunk
    const unsigned short* wb = bpack + (size_t)chunk * 294912 +
                               (size_t)((nblk << 3) + (wid << 1)) * 1024 +
                               (size_t)lane * 8;
    // prefetch tap 0 fragments (drained by the barrier below)
#pragma unroll
    for (int ni = 0; ni < 2; ++ni)
#pragma unroll
      for (int kk = 0; kk < 2; ++kk)
        bq0[ni * 2 + kk] = *(const bf16x8*)(wb + ni * 1024 + kk * 512);
    __syncthreads();                   // A staged (vmcnt(0) drain), bq0 ready

#pragma unroll
    for (int tap = 0; tap < 9; ++tap) {
      auto& cur = (tap & 1) ? bq1 : bq0;
      auto& nxt = (tap & 1) ? bq0 : bq1;
      if (tap < 8) {
#pragma unroll
        for (int ni = 0; ni < 2; ++ni)
#pragma unroll
          for (int kk = 0; kk < 2; ++kk)
            nxt[ni * 2 + kk] =
                *(const bf16x8*)(wb + (tap + 1) * 32768 + ni * 1024 + kk * 512);
      }
      const int ky = tap / 3, kx = tap - ky * 3;
      const int axor = ((l15 + kx) & 7) << 4;
#pragma unroll
      for (int kk = 0; kk < 2; ++kk) {
        const int kbyte = (((kk << 5) + (lhi << 3)) << 1);
        bf16x8 af[8];
#pragma unroll
        for (int mi = 0; mi < 8; ++mi) {
          int r = (mi >> 2) + ky;
          int xx = ((mi & 3) << 4) + l15 + kx;
          int off = ((r * 66 + xx) << 7) + (kbyte ^ axor);
          af[mi] = *(const bf16x8*)((const char*)ldsA + off);
        }
#pragma unroll
        for (int mi = 0; mi < 8; ++mi)
#pragma unroll
          for (int ni = 0; ni < 2; ++ni)
            acc[mi][ni] = __builtin_amdgcn_mfma_f32_16x16x32_bf16(
                af[mi], cur[ni * 2 + kk], acc[mi][ni], 0, 0, 0);
      }
    }
  }

  // ---- epilogue ----
  const int colr = l15;
  const int rowm = lhi << 2;
  float sc[2], nz[2];
#pragma unroll
  for (int ni = 0; ni < 2; ++ni) {
    int co = co_base + (ni << 4) + colr;
    sc[ni] = scale[(b << 9) + co];
    nz[ni] = noise[co];
  }
#pragma unroll
  for (int mi = 0; mi < 8; ++mi) {
#pragma unroll
    for (int j = 0; j < 4; ++j) {
      int px = (mi << 4) + rowm + j;
      int py = y0 + (px >> 6);
      int xcol = px & 63;
      size_t base = ((size_t)((b << 6) + py) * 64 + xcol) * 512 + co_base + colr;
#pragma unroll
      for (int ni = 0; ni < 2; ++ni) {
        size_t idx = base + ((size_t)ni << 4);
        float v = acc[mi][ni][j] * sc[ni];
        v += ns0[idx] * nz[ni] + bias0[idx];
        v = fmaxf(v, 0.2f * v);
        v += ns1[idx] * nz[ni] + bias1[idx];
        v = fmaxf(v, 0.2f * v);
        out[idx] = v;
      }
    }
  }
}

// ---------- launch ----------
extern "C" void kernel_launch(void* const* d_in, const int* in_sizes, int n_in,
                              void* d_out, int out_size, void* d_ws, size_t ws_size,
                              hipStream_t stream) {
  const float* x     = (const float*)d_in[0];
  const float* w     = (const float*)d_in[1];
  const float* noise = (const float*)d_in[2];
  const float* y0k   = (const float*)d_in[3];
  const float* y0b   = (const float*)d_in[4];
  // d_in[5..6]: y1_* unused (second conv result discarded by the reference).
  const float* conv0 = (const float*)d_in[7];
  // d_in[8]: conv1 unused
  const float* ns0   = (const float*)d_in[9];
  const float* ns1   = (const float*)d_in[10];
  const float* bias0 = (const float*)d_in[11];
  const float* bias1 = (const float*)d_in[12];
  float* out = (float*)d_out;

  // workspace: xpad bf16 [8][66][66][512] 35,684,352 B; bpack bf16 4,718,592 B;
  //            scale f32 16,384 B; wsum f32 2,048 B
  char* ws = (char*)d_ws;
  unsigned short* xpad  = (unsigned short*)ws;
  unsigned short* bpack = (unsigned short*)(ws + 35684352);
  float* scale = (float*)(ws + 35684352 + 4718592);
  float* wsum  = (float*)(ws + 35684352 + 4718592 + 16384);

  k_zero<<<2, 256, 0, stream>>>(wsum);
  k_bpack<<<576, 256, 0, stream>>>(conv0, bpack, wsum);
  k_scale<<<16, 256, 0, stream>>>(w, y0k, y0b, wsum, scale);
  k_up<<<8712, 256, 0, stream>>>(x, xpad);
  k_conv<<<1024, 256, 0, stream>>>(xpad, bpack, scale, noise, ns0, ns1, bias0, bias1, out);
}

// Round 3
// 214.010 us; speedup vs baseline: 2.1641x; 1.0926x over previous
//
#include <hip/hip_runtime.h>
#include <stdint.h>

typedef __attribute__((ext_vector_type(8))) __bf16 bf16x8;
typedef __attribute__((ext_vector_type(4))) float f32x4;
typedef __attribute__((ext_vector_type(8))) unsigned short us8;

// ---------- helpers ----------
__device__ __forceinline__ unsigned short f2bf(float f) {
  unsigned u = __float_as_uint(f);
  unsigned r = u + 0x7fffu + ((u >> 16) & 1u);   // RNE
  return (unsigned short)(r >> 16);
}

__device__ __forceinline__ void gload16(const void* gptr, void* lptr) {
  __builtin_amdgcn_global_load_lds(
      (const __attribute__((address_space(1))) void*)gptr,
      (__attribute__((address_space(3))) void*)lptr, 16, 0, 0);
}

// ---------- prep: pack conv0 -> MFMA B fragments (bf16) + wsum partials ----------
// bpack layout: [chunk(8)][tap(9)][co16(32)][kk(2)][lane(64)][8] bf16
// lane l, elem e: co = co16*16 + (l&15); ci = chunk*64 + kk*32 + (l>>4)*8 + e
// wpart[chunk*9+tap][co] = partial sum of squares over that chunk's 64 ci
__global__ void k_bpack(const float* __restrict__ conv0,
                        unsigned short* __restrict__ bpack,
                        float* __restrict__ wpart) {
  __shared__ float tile[64][65];
  int bx = blockIdx.x;                 // 576 = 9 taps * 8 chunks * 8 co-blocks
  int tap = bx >> 6, rem = bx & 63;
  int chunk = rem >> 3, cb = rem & 7;
  int ci0 = chunk << 6, co0 = cb << 6;
  int ty = threadIdx.x >> 6, tx = threadIdx.x & 63;
#pragma unroll
  for (int k = 0; k < 16; ++k) {
    int ci = (k << 2) + ty;
    tile[ci][tx] = conv0[((size_t)(tap * 512 + ci0 + ci)) * 512 + co0 + tx];
  }
  __syncthreads();
  // partial sum of squares: 4 threads (ty) each handle 16 ci for column tx
  float p = 0.f;
#pragma unroll
  for (int q = 0; q < 16; ++q) {
    float v = tile[(ty << 4) + q][tx];
    p += v * v;
  }
  // reduce 4 partials via LDS
  __shared__ float red[4][64];
  red[ty][tx] = p;
  __syncthreads();
  if (ty == 0)
    wpart[(size_t)(chunk * 9 + tap) * 512 + co0 + tx] =
        red[0][tx] + red[1][tx] + red[2][tx] + red[3][tx];
  // pack: 512 fragment-lane slots, 2 per thread
#pragma unroll
  for (int s2 = 0; s2 < 2; ++s2) {
    int slot = (threadIdx.x << 1) + s2;
    int f = slot >> 6, l = slot & 63;
    int co16l = f >> 1, kk = f & 1;
    int col = (co16l << 4) + (l & 15);
    int cil = (kk << 5) + ((l >> 4) << 3);
    us8 o;
#pragma unroll
    for (int e = 0; e < 8; ++e) o[e] = f2bf(tile[cil + e][col]);
    size_t fi = (((size_t)chunk * 9 + tap) * 32 + (cb << 2) + co16l) * 2 + kk;
    *(us8*)(bpack + fi * 512 + (size_t)l * 8) = o;
  }
}

// ---------- prep: scale[b][co] = s0 * rsqrt(s0^2*wsum + 1e-8) ----------
__global__ void k_scale(const float* __restrict__ w, const float* __restrict__ y0k,
                        const float* __restrict__ y0b, const float* __restrict__ wpart,
                        float* __restrict__ scale) {
  int g = blockIdx.x * 256 + threadIdx.x;       // grid 16 -> 4096 = 8*512
  int b = g >> 9, co = g & 511;
  float s = y0b[co];
  const float* wr = w + b * 512;
  for (int ci = 0; ci < 512; ++ci) s += wr[ci] * y0k[ci * 512 + co];
  float ws = 0.f;
  for (int r = 0; r < 72; ++r) ws += wpart[(size_t)r * 512 + co];
  scale[g] = s * rsqrtf(s * s * ws + 1e-8f);
}

// ---------- prep: bilinear 2x upsample + zero-pad, f32 -> bf16 ----------
__global__ void k_up(const float* __restrict__ x, unsigned short* __restrict__ xpad) {
  int gid = blockIdx.x * 256 + threadIdx.x;     // total 8*66*66*64 = 2230272
  if (gid >= 8 * 66 * 66 * 64) return;
  int c0 = (gid & 63) << 3;                     // 8 channels per thread
  int pos = gid >> 6;
  int xx = pos % 66;
  int t = pos / 66;
  int yy = t % 66;
  int b = t / 66;
  unsigned short* dst = xpad + (size_t)pos * 512 + c0;
  us8 o;
  if (yy == 0 || yy == 65 || xx == 0 || xx == 65) {
#pragma unroll
    for (int i = 0; i < 8; ++i) o[i] = 0;
  } else {
    int y = yy - 1, xq = xx - 1;
    int jy = y >> 1, jx = xq >> 1;
    int r0, r1, cx0, cx1;
    float ay0, ay1, ax0, ax1;
    if ((y & 1) == 0) { r0 = jy > 0 ? jy - 1 : 0; r1 = jy;
      ay0 = jy > 0 ? 0.25f : 0.f; ay1 = jy > 0 ? 0.75f : 1.f;
    } else { r0 = jy; r1 = jy < 31 ? jy + 1 : 31;
      ay0 = jy < 31 ? 0.75f : 1.f; ay1 = jy < 31 ? 0.25f : 0.f; }
    if ((xq & 1) == 0) { cx0 = jx > 0 ? jx - 1 : 0; cx1 = jx;
      ax0 = jx > 0 ? 0.25f : 0.f; ax1 = jx > 0 ? 0.75f : 1.f;
    } else { cx0 = jx; cx1 = jx < 31 ? jx + 1 : 31;
      ax0 = jx < 31 ? 0.75f : 1.f; ax1 = jx < 31 ? 0.25f : 0.f; }
    const float* base = x + (size_t)b * 32 * 32 * 512 + c0;
    const f32x4* q00 = (const f32x4*)(base + (size_t)(r0 * 32 + cx0) * 512);
    const f32x4* q01 = (const f32x4*)(base + (size_t)(r0 * 32 + cx1) * 512);
    const f32x4* q10 = (const f32x4*)(base + (size_t)(r1 * 32 + cx0) * 512);
    const f32x4* q11 = (const f32x4*)(base + (size_t)(r1 * 32 + cx1) * 512);
#pragma unroll
    for (int h = 0; h < 2; ++h) {
      f32x4 a = q00[h], bb = q01[h], c = q10[h], d = q11[h];
#pragma unroll
      for (int e = 0; e < 4; ++e) {
        float v = ay0 * (ax0 * a[e] + ax1 * bb[e]) + ay1 * (ax0 * c[e] + ax1 * d[e]);
        o[h * 4 + e] = f2bf(v);
      }
    }
  }
  *(us8*)dst = o;
}

// ---------- main conv ----------
// Block 128px x 128co, 4 waves each 128px x 32co (mi=8, ni=2).
// Double-buffered A halo in LDS; ONE barrier per ci-chunk; next chunk's staging
// issued during tap-0 compute so the barrier drain finds completed loads.
__global__ __launch_bounds__(256) void k_conv(
    const unsigned short* __restrict__ xpad,
    const unsigned short* __restrict__ bpack,
    const float* __restrict__ scale,
    const float* __restrict__ noise,
    const float* __restrict__ ns0, const float* __restrict__ ns1,
    const float* __restrict__ bias0, const float* __restrict__ bias1,
    float* __restrict__ out)
{
  // 2 x (4 rows x 66 x 64ch) bf16 = 67584 B; reused as 4 x [128][33] f32 epilogue
  __shared__ __align__(16) unsigned short ldsA[2][16896];

  const int tid = threadIdx.x;
  const int wid = tid >> 6;
  const int lane = tid & 63;
  const int l15 = lane & 15, lhi = lane >> 4;

  const int bx = blockIdx.x;           // 1024
  const int nblk = (bx >> 1) & 3;
  const int mblk = ((bx >> 3) << 1) | (bx & 1);
  const int b = mblk >> 5;
  const int y0 = (mblk & 31) << 1;
  const int co_base = (nblk << 7) + (wid << 5);   // wave's 32-co slice

  f32x4 acc[8][2];
#pragma unroll
  for (int i = 0; i < 8; ++i) {
    acc[i][0] = f32x4{0.f, 0.f, 0.f, 0.f};
    acc[i][1] = f32x4{0.f, 0.f, 0.f, 0.f};
  }

  const size_t xb = (size_t)b * (66 * 66 * 512);
  const size_t wboff = (size_t)((nblk << 3) + (wid << 1)) * 1024 + (size_t)lane * 8;
  bf16x8 bq0[4], bq1[4];

  // ---- prologue: stage chunk 0, prefetch B(0, tap0) ----
  {
#pragma unroll
    for (int i = wid; i < 33; i += 4) {
      int g = (i << 6) + lane;
      int rx = g >> 3;
      int r = rx / 66;
      int xx = rx - r * 66;
      int cg = (g & 7) ^ (xx & 7);
      const unsigned short* src =
          xpad + xb + ((size_t)((y0 + r) * 66 + xx) << 9) + (cg << 3);
      gload16(src, (char*)ldsA[0] + (i << 10));
    }
    const unsigned short* wb = bpack + wboff;
#pragma unroll
    for (int ni = 0; ni < 2; ++ni)
#pragma unroll
      for (int kk = 0; kk < 2; ++kk)
        bq0[ni * 2 + kk] = *(const bf16x8*)(wb + ni * 1024 + kk * 512);
  }
  __syncthreads();

  for (int chunk = 0; chunk < 8; ++chunk) {
    const char* Acur = (const char*)ldsA[chunk & 1];
    const unsigned short* wb = bpack + (size_t)chunk * 294912 + wboff;

#pragma unroll
    for (int tap = 0; tap < 9; ++tap) {
      auto& cur = (tap & 1) ? bq1 : bq0;
      auto& nxt = (tap & 1) ? bq0 : bq1;
      // prefetch next tap's B fragments (tap 8 -> next chunk's tap 0)
      if (tap < 8) {
#pragma unroll
        for (int ni = 0; ni < 2; ++ni)
#pragma unroll
          for (int kk = 0; kk < 2; ++kk)
            nxt[ni * 2 + kk] =
                *(const bf16x8*)(wb + (tap + 1) * 32768 + ni * 1024 + kk * 512);
      } else if (chunk < 7) {
#pragma unroll
        for (int ni = 0; ni < 2; ++ni)
#pragma unroll
          for (int kk = 0; kk < 2; ++kk)
            nxt[ni * 2 + kk] =
                *(const bf16x8*)(wb + 294912 + ni * 1024 + kk * 512);
      }
      // during tap 0: issue next chunk's A staging into the other buffer
      if (tap == 0 && chunk < 7) {
        char* Anxt = (char*)ldsA[(chunk + 1) & 1];
        const int kc = (chunk + 1) << 6;
#pragma unroll
        for (int i = wid; i < 33; i += 4) {
          int g = (i << 6) + lane;
          int rx = g >> 3;
          int r = rx / 66;
          int xx = rx - r * 66;
          int cg = (g & 7) ^ (xx & 7);
          const unsigned short* src =
              xpad + xb + ((size_t)((y0 + r) * 66 + xx) << 9) + kc + (cg << 3);
          gload16(src, Anxt + (i << 10));
        }
      }
      const int ky = tap / 3, kx = tap - ky * 3;
      const int axor = ((l15 + kx) & 7) << 4;
#pragma unroll
      for (int kk = 0; kk < 2; ++kk) {
        const int kbyte = (((kk << 5) + (lhi << 3)) << 1);
        bf16x8 af[8];
#pragma unroll
        for (int mi = 0; mi < 8; ++mi) {
          int r = (mi >> 2) + ky;
          int xx = ((mi & 3) << 4) + l15 + kx;
          int off = ((r * 66 + xx) << 7) + (kbyte ^ axor);
          af[mi] = *(const bf16x8*)(Acur + off);
        }
        __builtin_amdgcn_s_setprio(1);
#pragma unroll
        for (int mi = 0; mi < 8; ++mi)
#pragma unroll
          for (int ni = 0; ni < 2; ++ni)
            acc[mi][ni] = __builtin_amdgcn_mfma_f32_16x16x32_bf16(
                af[mi], cur[ni * 2 + kk], acc[mi][ni], 0, 0, 0);
        __builtin_amdgcn_s_setprio(0);
      }
    }
    // tap 8 prefetched next chunk's tap0 into bq1; rotate to bq0
#pragma unroll
    for (int i = 0; i < 4; ++i) bq0[i] = bq1[i];
    __syncthreads();   // drains vmcnt: next-chunk A staged, all waves done with cur
  }

  // ---- epilogue via LDS transpose: thread -> 32 contiguous co ----
  float* ldsE = (float*)ldsA + wid * 4224;   // 128*33 floats per wave
  float sc[2];
#pragma unroll
  for (int ni = 0; ni < 2; ++ni)
    sc[ni] = scale[(b << 9) + co_base + (ni << 4) + l15];
#pragma unroll
  for (int mi = 0; mi < 8; ++mi)
#pragma unroll
    for (int ni = 0; ni < 2; ++ni)
#pragma unroll
      for (int j = 0; j < 4; ++j) {
        int px = (mi << 4) + (lhi << 2) + j;
        ldsE[px * 33 + (ni << 4) + l15] = acc[mi][ni][j] * sc[ni];
      }
  const int qd = lane & 7;                   // thread's co quad (fixed)
  const int hh = lane >> 3;
  const f32x4 nz4 = *(const f32x4*)(noise + co_base + (qd << 2));
#pragma unroll
  for (int q = 0; q < 16; ++q) {
    int px = (q << 3) + hh;
    f32x4 v = *(const f32x4*)(ldsE + px * 33 + (qd << 2));
    int py = y0 + (px >> 6), xcol = px & 63;
    size_t idx = (((size_t)((b << 6) + py) << 6) + xcol) * 512 + co_base + (qd << 2);
    f32x4 a0 = *(const f32x4*)(ns0 + idx);
    f32x4 b0 = *(const f32x4*)(bias0 + idx);
    f32x4 a1 = *(const f32x4*)(ns1 + idx);
    f32x4 b1 = *(const f32x4*)(bias1 + idx);
    f32x4 o;
#pragma unroll
    for (int e = 0; e < 4; ++e) {
      float v0 = v[e] + a0[e] * nz4[e] + b0[e];
      v0 = fmaxf(v0, 0.2f * v0);
      v0 = v0 + a1[e] * nz4[e] + b1[e];
      o[e] = fmaxf(v0, 0.2f * v0);
    }
    *(f32x4*)(out + idx) = o;
  }
}

// ---------- launch ----------
extern "C" void kernel_launch(void* const* d_in, const int* in_sizes, int n_in,
                              void* d_out, int out_size, void* d_ws, size_t ws_size,
                              hipStream_t stream) {
  const float* x     = (const float*)d_in[0];
  const float* w     = (const float*)d_in[1];
  const float* noise = (const float*)d_in[2];
  const float* y0k   = (const float*)d_in[3];
  const float* y0b   = (const float*)d_in[4];
  // d_in[5..6]: y1_* unused (second conv result discarded by the reference).
  const float* conv0 = (const float*)d_in[7];
  // d_in[8]: conv1 unused
  const float* ns0   = (const float*)d_in[9];
  const float* ns1   = (const float*)d_in[10];
  const float* bias0 = (const float*)d_in[11];
  const float* bias1 = (const float*)d_in[12];
  float* out = (float*)d_out;

  // workspace: xpad bf16 35,684,352 B; bpack bf16 4,718,592 B;
  //            scale f32 16,384 B; wpart f32 72*512*4 = 147,456 B
  char* ws = (char*)d_ws;
  unsigned short* xpad  = (unsigned short*)ws;
  unsigned short* bpack = (unsigned short*)(ws + 35684352);
  float* scale = (float*)(ws + 35684352 + 4718592);
  float* wpart = (float*)(ws + 35684352 + 4718592 + 16384);

  k_bpack<<<576, 256, 0, stream>>>(conv0, bpack, wpart);
  k_scale<<<16, 256, 0, stream>>>(w, y0k, y0b, wpart, scale);
  k_up<<<8712, 256, 0, stream>>>(x, xpad);
  k_conv<<<1024, 256, 0, stream>>>(xpad, bpack, scale, noise, ns0, ns1, bias0, bias1, out);
}